// Round 10
// baseline (843.280 us; speedup 1.0000x reference)
//
#include <hip/hip_runtime.h>
#include <math.h>

#define BATCH 4
#define S_LEN 2048
#define DM    1024
#define NH    16
#define DK    64

typedef __attribute__((ext_vector_type(8))) short short8;
typedef __attribute__((ext_vector_type(4))) float f32x4;

static __device__ __forceinline__ unsigned short bf_hi(float x) {
    union { float f; unsigned u; } c; c.f = x;
    return (unsigned short)(c.u >> 16);          // truncate; residual goes to lo
}
static __device__ __forceinline__ float bf_f(unsigned short h) {
    union { unsigned u; float f; } c; c.u = ((unsigned)h) << 16;
    return c.f;
}
static __device__ __forceinline__ unsigned short bf_rnd(float x) {
    union { float f; unsigned u; } c; c.f = x;
    unsigned r = c.u + 0x7fffu + ((c.u >> 16) & 1u);
    return (unsigned short)(r >> 16);
}

// ---------------------------------------------------------------------------
// Split-bf16 GEMM core: C = A @ W^T (both K-contiguous), 128x128 tile, BK=32,
// 4 waves, 4x4 MFMA tiles/wave, 3-term split product.  (unchanged from R9)
// ---------------------------------------------------------------------------
template<bool PRESPLIT_A, bool SPLIT_OUT>
__global__ __launch_bounds__(256, 3)
void gemm_k(const float* __restrict__ Af,
            const unsigned short* __restrict__ Agh,
            const unsigned short* __restrict__ Agl,
            const float* __restrict__ W,
            float* __restrict__ Cf,
            unsigned short* __restrict__ Ch,
            unsigned short* __restrict__ Cl,
            float scale, int M, int N, int K)
{
    __shared__ unsigned short Xh[128][40], Xl[128][40];
    __shared__ unsigned short Wh[128][40], Wl[128][40];

    const int tid  = threadIdx.x;
    const int lane = tid & 63;
    const int wid  = tid >> 6;
    const int lrow = lane & 15;
    const int lgrp = lane >> 4;
    const int bm = blockIdx.y * 128;
    const int bn = blockIdx.x * 128;
    const int wm = (wid & 1) * 64;
    const int wn = (wid >> 1) * 64;

    const f32x4 fzero = {0.f, 0.f, 0.f, 0.f};
    f32x4 acc[4][4];
#pragma unroll
    for (int i = 0; i < 4; ++i)
#pragma unroll
        for (int j = 0; j < 4; ++j) acc[i][j] = fzero;

    const int srow = tid >> 2;
    const int sc8  = (tid & 3) * 8;

    for (int kt = 0; kt < K; kt += 32) {
        if constexpr (PRESPLIT_A) {
#pragma unroll
            for (int p = 0; p < 2; ++p) {
                int pos = tid + p * 256;
                int row = pos >> 2;
                int c8  = (pos & 3) * 8;
                *(short8*)&Xh[row][c8] =
                    *(const short8*)(Agh + (size_t)(bm + row) * K + kt + c8);
                *(short8*)&Xl[row][c8] =
                    *(const short8*)(Agl + (size_t)(bm + row) * K + kt + c8);
            }
        } else {
#pragma unroll
            for (int i = 0; i < 2; ++i) {
                const int row = srow + i * 64;
                const float* xp = Af + (size_t)(bm + row) * K + kt + sc8;
                float4 a0 = *(const float4*)xp, a1 = *(const float4*)(xp + 4);
                float va[8] = {a0.x,a0.y,a0.z,a0.w,a1.x,a1.y,a1.z,a1.w};
                short8 xh, xl;
#pragma unroll
                for (int j = 0; j < 8; ++j) {
                    unsigned short h = bf_hi(va[j]);
                    xh[j] = (short)h; xl[j] = (short)bf_hi(va[j] - bf_f(h));
                }
                *(short8*)&Xh[row][sc8] = xh; *(short8*)&Xl[row][sc8] = xl;
            }
        }
#pragma unroll
        for (int i = 0; i < 2; ++i) {
            const int row = srow + i * 64;
            const float* wp = W + (size_t)(bn + row) * K + kt + sc8;
            float4 b0 = *(const float4*)wp, b1 = *(const float4*)(wp + 4);
            float vb[8] = {b0.x,b0.y,b0.z,b0.w,b1.x,b1.y,b1.z,b1.w};
            short8 wh, wl;
#pragma unroll
            for (int j = 0; j < 8; ++j) {
                unsigned short g = bf_hi(vb[j]);
                wh[j] = (short)g; wl[j] = (short)bf_hi(vb[j] - bf_f(g));
            }
            *(short8*)&Wh[row][sc8] = wh; *(short8*)&Wl[row][sc8] = wl;
        }
        __syncthreads();

        short8 ah[4], al[4], bh[4], bl[4];
#pragma unroll
        for (int t = 0; t < 4; ++t) {
            ah[t] = *(const short8*)&Xh[wm + t*16 + lrow][lgrp*8];
            al[t] = *(const short8*)&Xl[wm + t*16 + lrow][lgrp*8];
            bh[t] = *(const short8*)&Wh[wn + t*16 + lrow][lgrp*8];
            bl[t] = *(const short8*)&Wl[wn + t*16 + lrow][lgrp*8];
        }
#pragma unroll
        for (int mt = 0; mt < 4; ++mt)
#pragma unroll
            for (int nt = 0; nt < 4; ++nt) {
                acc[mt][nt] = __builtin_amdgcn_mfma_f32_16x16x32_bf16(ah[mt], bh[nt], acc[mt][nt], 0, 0, 0);
                acc[mt][nt] = __builtin_amdgcn_mfma_f32_16x16x32_bf16(ah[mt], bl[nt], acc[mt][nt], 0, 0, 0);
                acc[mt][nt] = __builtin_amdgcn_mfma_f32_16x16x32_bf16(al[mt], bh[nt], acc[mt][nt], 0, 0, 0);
            }
        __syncthreads();
    }

#pragma unroll
    for (int mt = 0; mt < 4; ++mt)
#pragma unroll
        for (int nt = 0; nt < 4; ++nt)
#pragma unroll
            for (int r = 0; r < 4; ++r) {
                const size_t idx = (size_t)(bm + wm + mt*16 + lgrp*4 + r) * N
                                 + bn + wn + nt*16 + lrow;
                if constexpr (SPLIT_OUT) {
                    float v = acc[mt][nt][r] * scale;
                    unsigned short h = bf_hi(v);
                    Ch[idx] = h;
                    Cl[idx] = bf_hi(v - bf_f(h));
                } else {
                    Cf[idx] = acc[mt][nt][r];
                }
            }
}

// ---------------------------------------------------------------------------
// MFMA flash attention, causal, pre-split operands.
// R10 changes vs R9:
//  * QBLK 128: 4 waves x 32 q-rows (2 row-tiles of 16 each) -> half the
//    tile-iterations, 2x MFMA per barrier slot. Fully-masked row-tiles skipped.
//  * Async-STAGE split (T14): tile kt+1's K/V global loads issue into
//    registers during tile kt's compute; regs dump to LDS after the barrier.
// Same per-row arithmetic/order as R9 -> bit-identical output.
// ---------------------------------------------------------------------------
__global__ __launch_bounds__(256, 3)
void attn_mfma(const unsigned short* __restrict__ Qh_g, const unsigned short* __restrict__ Ql_g,
               const unsigned short* __restrict__ Kh_g, const unsigned short* __restrict__ Kl_g,
               const unsigned short* __restrict__ Vh_g, const unsigned short* __restrict__ Vl_g,
               unsigned short* __restrict__ Oh_g, unsigned short* __restrict__ Ol_g)
{
    __shared__ unsigned short Ksh[64][72], Ksl[64][72];  // [key][d]
    __shared__ unsigned short Vth[64][72], Vtl[64][72];  // [d][key] (transposed)
    __shared__ unsigned short Ps[4][16][72];             // per-wave P [q][key]

    const int tid  = threadIdx.x;
    const int lane = tid & 63;
    const int wid  = tid >> 6;
    const int lrow = lane & 15;
    const int lgrp = lane >> 4;

    const int qb = (int)(gridDim.x - 1u - blockIdx.x);   // long jobs first
    const int bh = blockIdx.y;
    const int b  = bh >> 4;
    const int h  = bh & 15;

    const size_t base = (size_t)b * S_LEN * DM + (size_t)h * DK;
    const int row0  = qb * 128;
    const int ktmax = 2 * qb + 1;

    // Q fragments for both row-tiles (pre-scaled by 1/8 in the Q GEMM)
    short8 qh[2][2], ql[2][2];
#pragma unroll
    for (int rt = 0; rt < 2; ++rt)
#pragma unroll
        for (int c = 0; c < 2; ++c) {
            const size_t qoff = base + (size_t)(row0 + wid*32 + rt*16 + lrow) * DM
                              + c*32 + lgrp*8;
            qh[rt][c] = *(const short8*)(Qh_g + qoff);
            ql[rt][c] = *(const short8*)(Ql_g + qoff);
        }

    const f32x4 fzero = {0.f, 0.f, 0.f, 0.f};
    f32x4 o[2][4];
    float m[2][4], l[2][4];
#pragma unroll
    for (int rt = 0; rt < 2; ++rt)
#pragma unroll
        for (int i = 0; i < 4; ++i) { o[rt][i] = fzero; m[rt][i] = -1e30f; l[rt][i] = 0.f; }

    const int skey = tid >> 3;           // K staging row (i adds 32)
    const int sc8  = (tid & 7) * 8;      // d-chunk
    const int vk0  = (tid >> 4) * 4;     // V staging 4x4 block: key base
    const int vd0  = (tid & 15) * 4;     //                      d base

    // prefetch registers (tile kt+1 in flight during tile kt compute)
    short8  pkh[2], pkl[2];
    ushort4 pvh[4], pvl[4];

    // prologue: load tile 0 into regs
    {
        const size_t kb = base;
#pragma unroll
        for (int i = 0; i < 2; ++i) {
            const size_t off = kb + (size_t)(skey + i*32) * DM + sc8;
            pkh[i] = *(const short8*)(Kh_g + off);
            pkl[i] = *(const short8*)(Kl_g + off);
        }
#pragma unroll
        for (int kk = 0; kk < 4; ++kk) {
            const size_t off = kb + (size_t)(vk0 + kk) * DM + vd0;
            pvh[kk] = *(const ushort4*)(Vh_g + off);
            pvl[kk] = *(const ushort4*)(Vl_g + off);
        }
    }

    for (int kt = 0; kt <= ktmax; ++kt) {
        // --- (A) dump prefetched tile kt into LDS
#pragma unroll
        for (int i = 0; i < 2; ++i) {
            *(short8*)&Ksh[skey + i*32][sc8] = pkh[i];
            *(short8*)&Ksl[skey + i*32][sc8] = pkl[i];
        }
#pragma unroll
        for (int j = 0; j < 4; ++j) {
            const unsigned short* e0 = (const unsigned short*)&pvh[0];
            const unsigned short* e1 = (const unsigned short*)&pvh[1];
            const unsigned short* e2 = (const unsigned short*)&pvh[2];
            const unsigned short* e3 = (const unsigned short*)&pvh[3];
            uint2 wh, wl;
            wh.x = (unsigned)e0[j] | ((unsigned)e1[j] << 16);
            wh.y = (unsigned)e2[j] | ((unsigned)e3[j] << 16);
            const unsigned short* f0 = (const unsigned short*)&pvl[0];
            const unsigned short* f1 = (const unsigned short*)&pvl[1];
            const unsigned short* f2 = (const unsigned short*)&pvl[2];
            const unsigned short* f3 = (const unsigned short*)&pvl[3];
            wl.x = (unsigned)f0[j] | ((unsigned)f1[j] << 16);
            wl.y = (unsigned)f2[j] | ((unsigned)f3[j] << 16);
            *(uint2*)&Vth[vd0 + j][vk0] = wh;
            *(uint2*)&Vtl[vd0 + j][vk0] = wl;
        }
        __syncthreads();

        // --- (B1) issue prefetch for tile kt+1 (latency hides under compute)
        if (kt < ktmax) {
            const size_t kb = base + (size_t)((kt + 1) * 64) * DM;
#pragma unroll
            for (int i = 0; i < 2; ++i) {
                const size_t off = kb + (size_t)(skey + i*32) * DM + sc8;
                pkh[i] = *(const short8*)(Kh_g + off);
                pkl[i] = *(const short8*)(Kl_g + off);
            }
#pragma unroll
            for (int kk = 0; kk < 4; ++kk) {
                const size_t off = kb + (size_t)(vk0 + kk) * DM + vd0;
                pvh[kk] = *(const ushort4*)(Vh_g + off);
                pvl[kk] = *(const ushort4*)(Vl_g + off);
            }
        }

        // --- (B2) compute both row-tiles against tile kt
#pragma unroll
        for (int rt = 0; rt < 2; ++rt) {
            const int qbase = wid * 32 + rt * 16;      // local q-row base
            if (kt * 64 > row0 + qbase + 15) continue; // fully-masked row-tile

            f32x4 s[4];
#pragma unroll
            for (int t = 0; t < 4; ++t) s[t] = fzero;
#pragma unroll
            for (int t = 0; t < 4; ++t)
#pragma unroll
                for (int c = 0; c < 2; ++c) {
                    short8 kh = *(const short8*)&Ksh[t*16 + lrow][c*32 + lgrp*8];
                    short8 kl = *(const short8*)&Ksl[t*16 + lrow][c*32 + lgrp*8];
                    s[t] = __builtin_amdgcn_mfma_f32_16x16x32_bf16(qh[rt][c], kh, s[t], 0, 0, 0);
                    s[t] = __builtin_amdgcn_mfma_f32_16x16x32_bf16(ql[rt][c], kh, s[t], 0, 0, 0);
                    s[t] = __builtin_amdgcn_mfma_f32_16x16x32_bf16(qh[rt][c], kl, s[t], 0, 0, 0);
                }

            if (kt * 64 + 63 > row0 + qbase) {         // partially-masked tile
#pragma unroll
                for (int t = 0; t < 4; ++t)
#pragma unroll
                    for (int r = 0; r < 4; ++r)
                        if (kt*64 + t*16 + lrow > row0 + qbase + lgrp*4 + r)
                            s[t][r] = -1e30f;
            }

            // online softmax
            float pm[4];
#pragma unroll
            for (int r = 0; r < 4; ++r)
                pm[r] = fmaxf(fmaxf(s[0][r], s[1][r]), fmaxf(s[2][r], s[3][r]));
#pragma unroll
            for (int off = 8; off >= 1; off >>= 1)
#pragma unroll
                for (int r = 0; r < 4; ++r)
                    pm[r] = fmaxf(pm[r], __shfl_xor(pm[r], off));

            float rs[4], rowsum[4];
#pragma unroll
            for (int r = 0; r < 4; ++r) {
                float mn = fmaxf(m[rt][r], pm[r]);
                rs[r] = __expf(m[rt][r] - mn);
                m[rt][r] = mn;
                rowsum[r] = 0.f;
            }
#pragma unroll
            for (int t = 0; t < 4; ++t)
#pragma unroll
                for (int r = 0; r < 4; ++r) {
                    float p = __expf(s[t][r] - m[rt][r]);
                    s[t][r] = p;
                    rowsum[r] += p;
                }
#pragma unroll
            for (int off = 8; off >= 1; off >>= 1)
#pragma unroll
                for (int r = 0; r < 4; ++r)
                    rowsum[r] += __shfl_xor(rowsum[r], off);
#pragma unroll
            for (int r = 0; r < 4; ++r) l[rt][r] = l[rt][r] * rs[r] + rowsum[r];
#pragma unroll
            for (int dt = 0; dt < 4; ++dt)
#pragma unroll
                for (int r = 0; r < 4; ++r) o[rt][dt][r] *= rs[r];

            // publish P as bf16 (wave-private; lgkmcnt orders reuse across rt)
#pragma unroll
            for (int t = 0; t < 4; ++t)
#pragma unroll
                for (int r = 0; r < 4; ++r)
                    Ps[wid][lgrp*4 + r][t*16 + lrow] = bf_rnd(s[t][r]);

            // O += P V (V 2-term split)
#pragma unroll
            for (int kc = 0; kc < 2; ++kc) {
                short8 pa = *(const short8*)&Ps[wid][lrow][kc*32 + lgrp*8];
#pragma unroll
                for (int dt = 0; dt < 4; ++dt) {
                    short8 vh = *(const short8*)&Vth[dt*16 + lrow][kc*32 + lgrp*8];
                    short8 vl = *(const short8*)&Vtl[dt*16 + lrow][kc*32 + lgrp*8];
                    o[rt][dt] = __builtin_amdgcn_mfma_f32_16x16x32_bf16(pa, vh, o[rt][dt], 0, 0, 0);
                    o[rt][dt] = __builtin_amdgcn_mfma_f32_16x16x32_bf16(pa, vl, o[rt][dt], 0, 0, 0);
                }
            }
        }
        __syncthreads();
    }

    // --- epilogue: normalize, split, store both planes
#pragma unroll
    for (int rt = 0; rt < 2; ++rt)
#pragma unroll
        for (int r = 0; r < 4; ++r) {
            float inv = 1.f / l[rt][r];
#pragma unroll
            for (int dt = 0; dt < 4; ++dt) {
                const size_t idx = base
                    + (size_t)(row0 + wid*32 + rt*16 + lgrp*4 + r) * DM + dt*16 + lrow;
                float v = o[rt][dt][r] * inv;
                unsigned short hh = bf_hi(v);
                Oh_g[idx] = hh;
                Ol_g[idx] = bf_hi(v - bf_f(hh));
            }
        }
}

// ---------------------------------------------------------------------------
extern "C" void kernel_launch(void* const* d_in, const int* in_sizes, int n_in,
                              void* d_out, int out_size, void* d_ws, size_t ws_size,
                              hipStream_t stream)
{
    const float* q   = (const float*)d_in[0];
    // d_in[1] = causal mask (static) -> ignored
    const float* w_q = (const float*)d_in[2];
    const float* w_k = (const float*)d_in[3];
    const float* w_v = (const float*)d_in[4];
    const float* w_o = (const float*)d_in[5];
    float* out = (float*)d_out;

    const size_t HN = (size_t)BATCH * S_LEN * DM;   // 8388608 elems, 16 MB/plane
    unsigned short* Qh = (unsigned short*)d_ws;
    unsigned short* Ql = Qh + HN;
    unsigned short* Kh = Ql + HN;
    unsigned short* Kl = Kh + HN;
    unsigned short* Vh = Kl + HN;
    unsigned short* Vl = Vh + HN;                   // total 96 MB
    // Attention output aliases Q planes (block-exclusive rows, read-before-write)
    unsigned short* Oh = Qh;
    unsigned short* Ol = Ql;

    const int M = BATCH * S_LEN;            // 8192
    dim3 blk(256);
    dim3 ggrid(DM / 128, M / 128);          // (8, 64)
    gemm_k<false, true><<<ggrid, blk, 0, stream>>>(q, nullptr, nullptr, w_q,
                                                   nullptr, Qh, Ql, 0.125f, M, DM, DM);
    gemm_k<false, true><<<ggrid, blk, 0, stream>>>(q, nullptr, nullptr, w_k,
                                                   nullptr, Kh, Kl, 1.0f, M, DM, DM);
    gemm_k<false, true><<<ggrid, blk, 0, stream>>>(q, nullptr, nullptr, w_v,
                                                   nullptr, Vh, Vl, 1.0f, M, DM, DM);

    dim3 agrid(S_LEN / 128, BATCH * NH);    // (16, 64) — QBLK=128
    attn_mfma<<<agrid, blk, 0, stream>>>(Qh, Ql, Kh, Kl, Vh, Vl, Oh, Ol);

    gemm_k<true, false><<<ggrid, blk, 0, stream>>>(nullptr, Oh, Ol, w_o,
                                                   out, nullptr, nullptr, 1.0f, M, DM, DM);
}